// Round 4
// baseline (197.076 us; speedup 1.0000x reference)
//
#include <hip/hip_runtime.h>
#include <hip/hip_bf16.h>

// ---------------------------------------------------------------------------
// Tree-MLP, round 4: level-parallel kernels.
//   k1: leaf(LDS) -> l7(LDS) -> l6(global h6)      [10240 blocks x 512]
//   k2: l5 (h6 global children, LDS) -> l4 (h4)    [2560 x 256]
//   k3: l3..l0 single-wave, LDS ping-pong, no bars [2560 x 64]
// Fallback to the round-3 per-tree kernel if ws_size is too small.
// ---------------------------------------------------------------------------

typedef __attribute__((ext_vector_type(8))) short s8v;   // 8 bf16
typedef __attribute__((ext_vector_type(4))) float f4v;   // MFMA C/D
typedef unsigned short u16;

__device__ __forceinline__ u16 f2bf(float f) {
    return __builtin_bit_cast(u16, __float2bfloat16(f));
}
__device__ __forceinline__ f4v mfma16(s8v a, s8v b, f4v c) {
    return __builtin_amdgcn_mfma_f32_16x16x32_bf16(a, b, c, 0, 0, 0);
}
// LDS swizzle: 8-granular XOR of h-index with row bits {0,2,3}
#define SWZ(r) ((((r) & 1) | (((r) >> 1) & 6)) << 3)

// x0 A-fragment for one 16-row tile: row = node row (incl. lm), k-slices:
// a0 = k[lq*8..+7] of 0..31, a1 = k 32..34 (lq==0 only)
__device__ __forceinline__ void xfrag(const float* __restrict__ xb, int row, int lq,
                                      s8v& a0, s8v& a1) {
    const float* xr = xb + (size_t)row * 35;
    float4 A = *(const float4*)(xr + lq * 8);
    float4 B = *(const float4*)(xr + lq * 8 + 4);
    a0[0]=(short)f2bf(A.x); a0[1]=(short)f2bf(A.y); a0[2]=(short)f2bf(A.z); a0[3]=(short)f2bf(A.w);
    a0[4]=(short)f2bf(B.x); a0[5]=(short)f2bf(B.y); a0[6]=(short)f2bf(B.z); a0[7]=(short)f2bf(B.w);
    a1 = (s8v){0,0,0,0,0,0,0,0};
    if (lq == 0) { a1[0]=(short)f2bf(xr[32]); a1[1]=(short)f2bf(xr[33]); a1[2]=(short)f2bf(xr[34]); }
}

// ---------------------------------------------------------------------------
__global__ void prep_kernel(const float* __restrict__ W_emb, const float* __restrict__ b_emb,
                            const float* __restrict__ W0, const float* __restrict__ b0,
                            const float* __restrict__ W1, const float* __restrict__ b1,
                            u16* __restrict__ wt1, u16* __restrict__ wt0,
                            float* __restrict__ b1p, float* __restrict__ b0p)
{
    int idx = blockIdx.x * 256 + threadIdx.x;
    if (idx < 64 * 192) {
        int h = idx / 192, k = idx % 192;
        float v;
        if (k < 32) { v = 0.f; for (int e = 0; e < 64; e++) v = fmaf(W1[h*195+e], W_emb[e*32+k], v); }
        else if (k < 35)  v = W1[h*195 + 64 + (k - 32)];
        else if (k < 64)  v = 0.f;
        else              v = W1[h*195 + 67 + (k - 64)];   // hL(64) then hR(64)
        wt1[h*192 + k] = f2bf(v);
    } else if (idx < 64*192 + 64*64) {
        int j = idx - 64*192; int h = j >> 6, k = j & 63;
        float v;
        if (k < 32)      { v = 0.f; for (int e = 0; e < 64; e++) v = fmaf(W0[h*67+e], W_emb[e*32+k], v); }
        else if (k < 35)   v = W0[h*67 + 64 + (k - 32)];
        else               v = 0.f;
        wt0[h*64 + k] = f2bf(v);
    } else if (idx < 64*192 + 64*64 + 64) {
        int h = idx - (64*192 + 64*64);
        float v = b1[h];
        for (int e = 0; e < 64; e++) v = fmaf(W1[h*195+e], b_emb[e], v);
        b1p[h] = v;
    } else if (idx < 64*192 + 64*64 + 128) {
        int h = idx - (64*192 + 64*64 + 64);
        float v = b0[h];
        for (int e = 0; e < 64; e++) v = fmaf(W0[h*67+e], b_emb[e], v);
        b0p[h] = v;
    }
}

// ---------------------------------------------------------------------------
// k1: block = (tree p, l6-tile q). leaf 64 rows -> LDS, l7 32 rows -> LDS,
// l6 16 rows -> global h6[p][64][64] bf16.
__global__ __launch_bounds__(512) void k1_leaf76(
    const float* __restrict__ x0,
    const u16* __restrict__ wt1, const u16* __restrict__ wt0,
    const float* __restrict__ b1p, const float* __restrict__ b0p,
    u16* __restrict__ h6)
{
    __shared__ __align__(16) u16 leafbuf[64 * 64];  // 8 KB
    __shared__ __align__(16) u16 l7buf[32 * 64];    // 4 KB
    const int l  = threadIdx.x & 63;
    const int w  = threadIdx.x >> 6;   // 0..7
    const int lq = l >> 4, lm = l & 15;
    const int p  = blockIdx.x >> 2, q = blockIdx.x & 3;
    const float* xb = x0 + (size_t)p * 511 * 35;

    // wt1 B-frags (used by phases 2 and 3): col = (w&3)*16 + lm
    const int colB = (w & 3) * 16 + lm;
    s8v wb1[6];
    #pragma unroll
    for (int ks = 0; ks < 6; ks++) wb1[ks] = *(const s8v*)(wt1 + colB*192 + ks*32 + lq*8);
    const float bv1 = b1p[colB];

    // ---- phase 1: leaf (4 tiles x 2 col-halves = 8 wave-jobs) ----
    {
        const int t = w >> 1, c = w & 1;
        s8v a0, a1;
        xfrag(xb, 255 + 64*q + 16*t + lm, lq, a0, a1);
        f4v acc[2]; s8v w0f[2][2];
        #pragma unroll
        for (int cc = 0; cc < 2; cc++) {
            int col = c*32 + cc*16 + lm;
            w0f[cc][0] = *(const s8v*)(wt0 + col*64 +      lq*8);
            w0f[cc][1] = *(const s8v*)(wt0 + col*64 + 32 + lq*8);
            float bv = b0p[col];
            acc[cc] = (f4v){bv, bv, bv, bv};
        }
        #pragma unroll
        for (int cc = 0; cc < 2; cc++) {
            acc[cc] = mfma16(a0, w0f[cc][0], acc[cc]);
            acc[cc] = mfma16(a1, w0f[cc][1], acc[cc]);
        }
        #pragma unroll
        for (int r = 0; r < 4; r++) {
            int ro = 16*t + lq*4 + r; int sw = SWZ(ro);
            #pragma unroll
            for (int cc = 0; cc < 2; cc++)
                leafbuf[ro*64 + ((c*32 + cc*16 + lm) ^ sw)] = f2bf(fmaxf(acc[cc][r], 0.f));
        }
    }
    __syncthreads();

    // ---- phase 2: l7 (2 tiles x 4 col-quarters = 8 wave-jobs) ----
    {
        const int t = w >> 2;
        s8v a0, a1;
        xfrag(xb, 127 + 32*q + 16*t + lm, lq, a0, a1);
        f4v acc = (f4v){bv1, bv1, bv1, bv1};
        acc = mfma16(a0, wb1[0], acc);
        acc = mfma16(a1, wb1[1], acc);
        #pragma unroll
        for (int ks = 0; ks < 4; ks++) {
            int k0 = ks*32 + lq*8;
            int rr = 2*(16*t + lm) + (k0 >> 6);
            s8v a = *(const s8v*)(leafbuf + rr*64 + ((k0 & 63) ^ SWZ(rr)));
            acc = mfma16(a, wb1[2 + ks], acc);
        }
        #pragma unroll
        for (int r = 0; r < 4; r++) {
            int ro = 16*t + lq*4 + r; int sw = SWZ(ro);
            l7buf[ro*64 + (colB ^ sw)] = f2bf(fmaxf(acc[r], 0.f));
        }
    }
    __syncthreads();

    // ---- phase 3: l6 (1 tile x 4 col-quarters, waves 0..3) ----
    if (w < 4) {
        s8v a0, a1;
        xfrag(xb, 63 + 16*q + lm, lq, a0, a1);
        f4v acc = (f4v){bv1, bv1, bv1, bv1};
        acc = mfma16(a0, wb1[0], acc);
        acc = mfma16(a1, wb1[1], acc);
        #pragma unroll
        for (int ks = 0; ks < 4; ks++) {
            int k0 = ks*32 + lq*8;
            int rr = 2*lm + (k0 >> 6);
            s8v a = *(const s8v*)(l7buf + rr*64 + ((k0 & 63) ^ SWZ(rr)));
            acc = mfma16(a, wb1[2 + ks], acc);
        }
        #pragma unroll
        for (int r = 0; r < 4; r++)
            h6[((size_t)p*64 + 16*q + lq*4 + r) * 64 + colB] = f2bf(fmaxf(acc[r], 0.f));
    }
}

// ---------------------------------------------------------------------------
// k2: block = tree p. l5 32 rows (children from h6 global) -> LDS,
// l4 16 rows -> global h4[p][16][64] bf16.
__global__ __launch_bounds__(256) void k2_l54(
    const float* __restrict__ x0,
    const u16* __restrict__ wt1, const float* __restrict__ b1p,
    const u16* __restrict__ h6, u16* __restrict__ h4)
{
    __shared__ __align__(16) u16 l5buf[32 * 64];    // 4 KB
    const int l  = threadIdx.x & 63;
    const int w  = threadIdx.x >> 6;   // 0..3
    const int lq = l >> 4, lm = l & 15;
    const int p  = blockIdx.x;
    const float* xb = x0 + (size_t)p * 511 * 35;

    // ---- phase 1: l5 (2 tiles x 2 col-halves = 4 wave-jobs) ----
    {
        const int t = w >> 1, c = w & 1;
        const int j5 = 16*t + lm;
        s8v a0, a1;
        xfrag(xb, 31 + j5, lq, a0, a1);
        f4v acc[2]; s8v wb[2][6];
        #pragma unroll
        for (int cc = 0; cc < 2; cc++) {
            int col = c*32 + cc*16 + lm;
            #pragma unroll
            for (int ks = 0; ks < 6; ks++) wb[cc][ks] = *(const s8v*)(wt1 + col*192 + ks*32 + lq*8);
            float bv = b1p[col];
            acc[cc] = (f4v){bv, bv, bv, bv};
        }
        #pragma unroll
        for (int cc = 0; cc < 2; cc++) {
            acc[cc] = mfma16(a0, wb[cc][0], acc[cc]);
            acc[cc] = mfma16(a1, wb[cc][1], acc[cc]);
        }
        #pragma unroll
        for (int ks = 0; ks < 4; ks++) {
            int k0 = ks*32 + lq*8;
            int rr = 2*j5 + (k0 >> 6);                       // 0..63
            s8v a = *(const s8v*)(h6 + ((size_t)p*64 + rr)*64 + (k0 & 63));
            #pragma unroll
            for (int cc = 0; cc < 2; cc++) acc[cc] = mfma16(a, wb[cc][2 + ks], acc[cc]);
        }
        #pragma unroll
        for (int r = 0; r < 4; r++) {
            int ro = 16*t + lq*4 + r; int sw = SWZ(ro);
            #pragma unroll
            for (int cc = 0; cc < 2; cc++)
                l5buf[ro*64 + ((c*32 + cc*16 + lm) ^ sw)] = f2bf(fmaxf(acc[cc][r], 0.f));
        }
    }
    __syncthreads();

    // ---- phase 2: l4 (1 tile x 4 col-quarters = 4 wave-jobs) ----
    {
        const int col = w*16 + lm;
        s8v wb[6];
        #pragma unroll
        for (int ks = 0; ks < 6; ks++) wb[ks] = *(const s8v*)(wt1 + col*192 + ks*32 + lq*8);
        float bv = b1p[col];
        s8v a0, a1;
        xfrag(xb, 15 + lm, lq, a0, a1);
        f4v acc = (f4v){bv, bv, bv, bv};
        acc = mfma16(a0, wb[0], acc);
        acc = mfma16(a1, wb[1], acc);
        #pragma unroll
        for (int ks = 0; ks < 4; ks++) {
            int k0 = ks*32 + lq*8;
            int rr = 2*lm + (k0 >> 6);                       // 0..31
            s8v a = *(const s8v*)(l5buf + rr*64 + ((k0 & 63) ^ SWZ(rr)));
            acc = mfma16(a, wb[2 + ks], acc);
        }
        #pragma unroll
        for (int r = 0; r < 4; r++)
            h4[((size_t)p*16 + lq*4 + r) * 64 + col] = f2bf(fmaxf(acc[r], 0.f));
    }
}

// ---------------------------------------------------------------------------
// k3: block = tree p, ONE wave. l3..l0, children via LDS ping-pong,
// no barriers (in-wave lgkmcnt ordering). Garbage rows never feed valid rows.
__global__ __launch_bounds__(64) void k3_tail(
    const float* __restrict__ x0,
    const u16* __restrict__ wt1, const float* __restrict__ b1p,
    const u16* __restrict__ h4, float* __restrict__ h0)
{
    __shared__ __align__(16) u16 tb0[32 * 64];   // 4 KB
    __shared__ __align__(16) u16 tb1[32 * 64];   // 4 KB
    const int l  = threadIdx.x;
    const int lq = l >> 4, lm = l & 15;
    const int p  = blockIdx.x;
    const float* xb = x0 + (size_t)p * 511 * 35;

    s8v wB[6][4]; f4v bi[4];
    #pragma unroll
    for (int ct = 0; ct < 4; ct++) {
        int col = ct*16 + lm;
        #pragma unroll
        for (int ks = 0; ks < 6; ks++) wB[ks][ct] = *(const s8v*)(wt1 + col*192 + ks*32 + lq*8);
        float bv = b1p[col];
        bi[ct] = (f4v){bv, bv, bv, bv};
    }

    f4v acc[4];
    auto store_lds = [&](u16* buf) {
        #pragma unroll
        for (int r = 0; r < 4; r++) {
            int ro = lq*4 + r; int sw = SWZ(ro);
            #pragma unroll
            for (int ct = 0; ct < 4; ct++)
                buf[ro*64 + ((ct*16 + lm) ^ sw)] = f2bf(fmaxf(acc[ct][r], 0.f));
        }
        asm volatile("s_waitcnt lgkmcnt(0)" ::: "memory");
    };

    // ---- l3 (children from h4 global; valid rows 0..7) ----
    {
        s8v a0, a1;
        xfrag(xb, 7 + lm, lq, a0, a1);
        #pragma unroll
        for (int ct = 0; ct < 4; ct++) acc[ct] = bi[ct];
        #pragma unroll
        for (int ct = 0; ct < 4; ct++) { acc[ct] = mfma16(a0, wB[0][ct], acc[ct]); acc[ct] = mfma16(a1, wB[1][ct], acc[ct]); }
        #pragma unroll
        for (int ks = 0; ks < 4; ks++) {
            int k0 = ks*32 + lq*8;
            int rr = 2*lm + (k0 >> 6);      // up to 31: overreads land in h0 region (allocated)
            s8v a = *(const s8v*)(h4 + ((size_t)p*16 + rr)*64 + (k0 & 63));
            #pragma unroll
            for (int ct = 0; ct < 4; ct++) acc[ct] = mfma16(a, wB[2 + ks][ct], acc[ct]);
        }
        store_lds(tb0);
    }

    // ---- l2, l1, l0 from LDS ----
    auto level = [&](int lo, const u16* bufR) {
        s8v a0, a1;
        xfrag(xb, lo + lm, lq, a0, a1);
        #pragma unroll
        for (int ct = 0; ct < 4; ct++) acc[ct] = bi[ct];
        #pragma unroll
        for (int ct = 0; ct < 4; ct++) { acc[ct] = mfma16(a0, wB[0][ct], acc[ct]); acc[ct] = mfma16(a1, wB[1][ct], acc[ct]); }
        #pragma unroll
        for (int ks = 0; ks < 4; ks++) {
            int k0 = ks*32 + lq*8;
            int rr = 2*lm + (k0 >> 6);      // <= 31, within 32-row buffer
            s8v a = *(const s8v*)(bufR + rr*64 + ((k0 & 63) ^ SWZ(rr)));
            #pragma unroll
            for (int ct = 0; ct < 4; ct++) acc[ct] = mfma16(a, wB[2 + ks][ct], acc[ct]);
        }
    };
    level(3, tb0); store_lds(tb1);
    level(1, tb1); store_lds(tb0);
    level(0, tb0);
    if (lq == 0) {
        #pragma unroll
        for (int ct = 0; ct < 4; ct++)
            h0[(size_t)p*64 + ct*16 + lm] = fmaxf(acc[ct][0], 0.f);
    }
}

// ---------------------------------------------------------------------------
// Fallback: round-3 per-tree kernel (known-passing), used if ws is too small.
struct XL { float4 A, B, T; };

__global__ __launch_bounds__(512, 4) void tree_kernel(
    const float* __restrict__ x0,
    const u16* __restrict__ wt1,
    const u16* __restrict__ wt0,
    const float* __restrict__ b1p,
    const float* __restrict__ b0p,
    float* __restrict__ h0out)
{
    __shared__ __align__(16) u16 buf0[256 * 64];
    __shared__ __align__(16) u16 buf1[128 * 64];

    const int l  = threadIdx.x & 63;
    const int w  = threadIdx.x >> 6;
    const int c2 = w & 1;
    const int wr = w >> 1;
    const int lq = l >> 4;
    const int lm = l & 15;
    const int p  = blockIdx.x;
    const float* xbase = x0 + (size_t)p * 511 * 35;

    auto BAR = []() {
        asm volatile("s_waitcnt lgkmcnt(0)" ::: "memory");
        __builtin_amdgcn_s_barrier();
        asm volatile("" ::: "memory");
    };
    auto xloadf = [&](int lo, int R0) -> XL {
        const float* xr = xbase + (size_t)(lo + R0 + lm) * 35;
        XL v;
        v.A = *(const float4*)(xr + lq * 8);
        v.B = *(const float4*)(xr + lq * 8 + 4);
        if (lq == 0) v.T = *(const float4*)(xr + 31);
        else         v.T = float4{0.f, 0.f, 0.f, 0.f};
        return v;
    };
    auto mk0 = [&](const XL& v) -> s8v {
        s8v r;
        r[0]=(short)f2bf(v.A.x); r[1]=(short)f2bf(v.A.y); r[2]=(short)f2bf(v.A.z); r[3]=(short)f2bf(v.A.w);
        r[4]=(short)f2bf(v.B.x); r[5]=(short)f2bf(v.B.y); r[6]=(short)f2bf(v.B.z); r[7]=(short)f2bf(v.B.w);
        return r;
    };
    auto mk1 = [&](const XL& v) -> s8v {
        s8v r = {0,0,0,0,0,0,0,0};
        r[0]=(short)f2bf(v.T.y); r[1]=(short)f2bf(v.T.z); r[2]=(short)f2bf(v.T.w);
        return r;
    };
    auto store16 = [&](u16* bufW, int R0, const f4v& acc0, const f4v& acc1) {
        #pragma unroll
        for (int r = 0; r < 4; r++) {
            int ro = R0 + lq * 4 + r;
            int sw = SWZ(ro);
            bufW[ro*64 + ((c2*32      + lm) ^ sw)] = f2bf(fmaxf(acc0[r], 0.f));
            bufW[ro*64 + ((c2*32 + 16 + lm) ^ sw)] = f2bf(fmaxf(acc1[r], 0.f));
        }
    };

    {
        XL xl[4];
        #pragma unroll
        for (int t = 0; t < 4; t++) xl[t] = xloadf(255, (wr + 4*t) * 16);
        s8v wL[2][2]; f4v bi0[2];
        #pragma unroll
        for (int cc = 0; cc < 2; cc++) {
            int col = c2*32 + cc*16 + lm;
            wL[cc][0] = *(const s8v*)(wt0 + col*64 +      lq*8);
            wL[cc][1] = *(const s8v*)(wt0 + col*64 + 32 + lq*8);
            float bv = b0p[col];
            bi0[cc] = (f4v){bv, bv, bv, bv};
        }
        #pragma unroll
        for (int t = 0; t < 4; t++) {
            int R0 = (wr + 4*t) * 16;
            s8v a0 = mk0(xl[t]), a1 = mk1(xl[t]);
            f4v acc0 = bi0[0], acc1 = bi0[1];
            acc0 = mfma16(a0, wL[0][0], acc0);
            acc1 = mfma16(a0, wL[1][0], acc1);
            acc0 = mfma16(a1, wL[0][1], acc0);
            acc1 = mfma16(a1, wL[1][1], acc1);
            store16(buf0, R0, acc0, acc1);
        }
    }

    s8v wX[2][2], wH[2][4]; f4v bi1[2];
    #pragma unroll
    for (int cc = 0; cc < 2; cc++) {
        int col = c2*32 + cc*16 + lm;
        #pragma unroll
        for (int ks = 0; ks < 2; ks++) wX[cc][ks] = *(const s8v*)(wt1 + col*192 + ks*32 + lq*8);
        #pragma unroll
        for (int ks = 0; ks < 4; ks++) wH[cc][ks] = *(const s8v*)(wt1 + col*192 + 64 + ks*32 + lq*8);
        float bv = b1p[col];
        bi1[cc] = (f4v){bv, bv, bv, bv};
    }

    auto child_frag = [&](const u16* bufR, int g, int ks) -> s8v {
        int k0 = ks*32 + lq*8;
        int rr = 2*g + (k0 >> 6);
        int off = (k0 & 63) ^ SWZ(rr);
        return *(const s8v*)(bufR + rr*64 + off);
    };
    auto ctile = [&](const u16* bufR, u16* bufW, const XL& xv, int R0) {
        s8v a0 = mk0(xv), a1 = mk1(xv);
        f4v acc0 = bi1[0], acc1 = bi1[1];
        acc0 = mfma16(a0, wX[0][0], acc0);
        acc1 = mfma16(a0, wX[1][0], acc1);
        acc0 = mfma16(a1, wX[0][1], acc0);
        acc1 = mfma16(a1, wX[1][1], acc1);
        int g = R0 + lm;
        #pragma unroll
        for (int ks = 0; ks < 4; ks++) {
            s8v a = child_frag(bufR, g, ks);
            acc0 = mfma16(a, wH[0][ks], acc0);
            acc1 = mfma16(a, wH[1][ks], acc1);
        }
        store16(bufW, R0, acc0, acc1);
    };

    XL x7a = xloadf(127, wr*16);
    XL x7b = xloadf(127, (wr + 4)*16);
    BAR();
    ctile(buf0, buf1, x7a, wr*16);
    ctile(buf0, buf1, x7b, (wr + 4)*16);

    XL x6 = xloadf(63, wr*16);
    BAR();
    ctile(buf1, buf0, x6, wr*16);

    XL x5; if (wr < 2) x5 = xloadf(31, wr*16);
    BAR();
    if (wr < 2) ctile(buf0, buf1, x5, wr*16);

    XL x4; if (wr == 0) x4 = xloadf(15, 0);
    BAR();
    if (wr == 0) ctile(buf1, buf0, x4, 0);

    XL x3; if (wr == 0) x3 = xloadf(7, 0);
    BAR();
    if (wr == 0) ctile(buf0, buf1, x3, 0);

    XL x2; if (wr == 0) x2 = xloadf(3, 0);
    BAR();
    if (wr == 0) ctile(buf1, buf0, x2, 0);

    XL x1; if (wr == 0) x1 = xloadf(1, 0);
    BAR();
    if (wr == 0) ctile(buf0, buf1, x1, 0);

    XL xz; if (wr == 0) xz = xloadf(0, 0);
    BAR();
    if (wr == 0) {
        s8v a0 = mk0(xz), a1 = mk1(xz);
        f4v acc0 = bi1[0], acc1 = bi1[1];
        acc0 = mfma16(a0, wX[0][0], acc0);
        acc1 = mfma16(a0, wX[1][0], acc1);
        acc0 = mfma16(a1, wX[0][1], acc0);
        acc1 = mfma16(a1, wX[1][1], acc1);
        #pragma unroll
        for (int ks = 0; ks < 4; ks++) {
            s8v a = child_frag(buf1, lm, ks);
            acc0 = mfma16(a, wH[0][ks], acc0);
            acc1 = mfma16(a, wH[1][ks], acc1);
        }
        if (lq == 0) {
            h0out[(size_t)p*64 + c2*32      + lm] = fmaxf(acc0[0], 0.f);
            h0out[(size_t)p*64 + c2*32 + 16 + lm] = fmaxf(acc1[0], 0.f);
        }
    }
}

// ---------------------------------------------------------------------------
__global__ void mean_kernel(const float* __restrict__ h0, float* __restrict__ mh)
{
    int idx = blockIdx.x * blockDim.x + threadIdx.x;   // 512*64
    if (idx < 512 * 64) {
        int g = idx >> 6, h = idx & 63;
        float s = 0.f;
        #pragma unroll
        for (int q = 0; q < 5; q++) s += h0[(size_t)(g * 5 + q) * 64 + h];
        mh[idx] = s * 0.2f;
    }
}

__global__ __launch_bounds__(64) void head_kernel(const float* __restrict__ x,
                                                  const float* __restrict__ mh,
                                                  const float* __restrict__ Wfc1,
                                                  const float* __restrict__ bfc1,
                                                  const float* __restrict__ Wfc2,
                                                  const float* __restrict__ bfc2,
                                                  float* __restrict__ out)
{
    __shared__ float sw[64];
    __shared__ float sh[64];
    int b = blockIdx.x, h = threadIdx.x;

    float a0 = 0.f, a1 = 0.f, a2 = 0.f, a3 = 0.f;
    const float* xr = x + (size_t)b * 512;
    for (int g = 0; g < 512; g += 4) {
        a0 = fmaf(xr[g + 0], mh[(g + 0) * 64 + h], a0);
        a1 = fmaf(xr[g + 1], mh[(g + 1) * 64 + h], a1);
        a2 = fmaf(xr[g + 2], mh[(g + 2) * 64 + h], a2);
        a3 = fmaf(xr[g + 3], mh[(g + 3) * 64 + h], a3);
    }
    sw[h] = (a0 + a1) + (a2 + a3);
    __syncthreads();

    float acc = bfc1[h];
    #pragma unroll 8
    for (int k = 0; k < 64; k++) acc = fmaf(Wfc1[h * 64 + k], sw[k], acc);
    sh[h] = fmaxf(acc, 0.f);
    __syncthreads();

    if (h < 8) {
        float o = bfc2[h];
        #pragma unroll 8
        for (int f = 0; f < 64; f++) o = fmaf(Wfc2[h * 64 + f], sh[f], o);
        out[(size_t)b * 8 + h] = o;
    }
}

// ---------------------------------------------------------------------------
extern "C" void kernel_launch(void* const* d_in, const int* in_sizes, int n_in,
                              void* d_out, int out_size, void* d_ws, size_t ws_size,
                              hipStream_t stream)
{
    (void)in_sizes; (void)n_in; (void)out_size;
    const float* x     = (const float*)d_in[0];
    const float* x0    = (const float*)d_in[1];
    const float* W_emb = (const float*)d_in[2];
    const float* b_emb = (const float*)d_in[3];
    const float* W0    = (const float*)d_in[4];
    const float* b0    = (const float*)d_in[5];
    const float* W1    = (const float*)d_in[6];
    const float* b1    = (const float*)d_in[7];
    const float* Wfc1  = (const float*)d_in[8];
    const float* bfc1  = (const float*)d_in[9];
    const float* Wfc2  = (const float*)d_in[10];
    const float* bfc2  = (const float*)d_in[11];
    float* out = (float*)d_out;

    u16* wt1   = (u16*)d_ws;            // 64*192
    u16* wt0   = wt1 + 64 * 192;        // 64*64
    float* b1p = (float*)(wt0 + 64 * 64);
    float* b0p = b1p + 64;

    // new-path layout
    u16* h6    = (u16*)(b0p + 64);                    // 2560*64*64
    u16* h4    = h6 + (size_t)2560 * 64 * 64;         // 2560*16*64
    float* h0n = (float*)(h4 + (size_t)2560 * 16 * 64);
    float* mhn = h0n + 2560 * 64;
    size_t need = (size_t)((char*)(mhn + 512 * 64) - (char*)d_ws);

    prep_kernel<<<65, 256, 0, stream>>>(W_emb, b_emb, W0, b0, W1, b1, wt1, wt0, b1p, b0p);

    if (ws_size >= need) {
        k1_leaf76<<<10240, 512, 0, stream>>>(x0, wt1, wt0, b1p, b0p, h6);
        k2_l54<<<2560, 256, 0, stream>>>(x0, wt1, b1p, h6, h4);
        k3_tail<<<2560, 64, 0, stream>>>(x0, wt1, b1p, h4, h0n);
        mean_kernel<<<128, 256, 0, stream>>>(h0n, mhn);
        head_kernel<<<512, 64, 0, stream>>>(x, mhn, Wfc1, bfc1, Wfc2, bfc2, out);
    } else {
        float* h0 = b0p + 64;           // old layout
        float* mh = h0 + 2560 * 64;
        tree_kernel<<<2560, 512, 0, stream>>>(x0, wt1, wt0, b1p, b0p, h0);
        mean_kernel<<<128, 256, 0, stream>>>(h0, mh);
        head_kernel<<<512, 64, 0, stream>>>(x, mh, Wfc1, bfc1, Wfc2, bfc2, out);
    }
}

// Round 5
// 118.227 us; speedup vs baseline: 1.6669x; 1.6669x over previous
//
#include <hip/hip_runtime.h>
#include <hip/hip_bf16.h>

// ---------------------------------------------------------------------------
// Tree-MLP, round 5.
//   tree_front: per-tree block, leaf->l7->l6->l5->l4 (4 barriers), deep x0
//               register prefetch (>=2 phases ahead), leaf 4-tile ILP,
//               writes h4 (16 rows/tree, bf16).
//   k3_tail:    per-tree single wave, l3..l0, no barriers, all loads hoisted.
// ---------------------------------------------------------------------------

typedef __attribute__((ext_vector_type(8))) short s8v;   // 8 bf16
typedef __attribute__((ext_vector_type(4))) float f4v;   // MFMA C/D
typedef unsigned short u16;

__device__ __forceinline__ u16 f2bf(float f) {
    return __builtin_bit_cast(u16, __float2bfloat16(f));
}
__device__ __forceinline__ f4v mfma16(s8v a, s8v b, f4v c) {
    return __builtin_amdgcn_mfma_f32_16x16x32_bf16(a, b, c, 0, 0, 0);
}
// LDS swizzle: 8-granular XOR of h-index with row bits {0,2,3}
#define SWZ(r) ((((r) & 1) | (((r) >> 1) & 6)) << 3)

struct XL { float4 A, B, T; };   // raw f32 x0 fragment

__device__ __forceinline__ s8v mk0(const XL& v) {
    s8v r;
    r[0]=(short)f2bf(v.A.x); r[1]=(short)f2bf(v.A.y); r[2]=(short)f2bf(v.A.z); r[3]=(short)f2bf(v.A.w);
    r[4]=(short)f2bf(v.B.x); r[5]=(short)f2bf(v.B.y); r[6]=(short)f2bf(v.B.z); r[7]=(short)f2bf(v.B.w);
    return r;
}
__device__ __forceinline__ s8v mk1(const XL& v) {   // k32..34 (lq==0 lanes only)
    s8v r = {0,0,0,0,0,0,0,0};
    r[0]=(short)f2bf(v.T.y); r[1]=(short)f2bf(v.T.z); r[2]=(short)f2bf(v.T.w);
    return r;
}

// ---------------------------------------------------------------------------
__global__ void prep_kernel(const float* __restrict__ W_emb, const float* __restrict__ b_emb,
                            const float* __restrict__ W0, const float* __restrict__ b0,
                            const float* __restrict__ W1, const float* __restrict__ b1,
                            u16* __restrict__ wt1, u16* __restrict__ wt0,
                            float* __restrict__ b1p, float* __restrict__ b0p)
{
    int idx = blockIdx.x * 256 + threadIdx.x;
    if (idx < 64 * 192) {
        int h = idx / 192, k = idx % 192;
        float v;
        if (k < 32) { v = 0.f; for (int e = 0; e < 64; e++) v = fmaf(W1[h*195+e], W_emb[e*32+k], v); }
        else if (k < 35)  v = W1[h*195 + 64 + (k - 32)];
        else if (k < 64)  v = 0.f;
        else              v = W1[h*195 + 67 + (k - 64)];   // hL(64) then hR(64)
        wt1[h*192 + k] = f2bf(v);
    } else if (idx < 64*192 + 64*64) {
        int j = idx - 64*192; int h = j >> 6, k = j & 63;
        float v;
        if (k < 32)      { v = 0.f; for (int e = 0; e < 64; e++) v = fmaf(W0[h*67+e], W_emb[e*32+k], v); }
        else if (k < 35)   v = W0[h*67 + 64 + (k - 32)];
        else               v = 0.f;
        wt0[h*64 + k] = f2bf(v);
    } else if (idx < 64*192 + 64*64 + 64) {
        int h = idx - (64*192 + 64*64);
        float v = b1[h];
        for (int e = 0; e < 64; e++) v = fmaf(W1[h*195+e], b_emb[e], v);
        b1p[h] = v;
    } else if (idx < 64*192 + 64*64 + 128) {
        int h = idx - (64*192 + 64*64 + 64);
        float v = b0[h];
        for (int e = 0; e < 64; e++) v = fmaf(W0[h*67+e], b_emb[e], v);
        b0p[h] = v;
    }
}

// ---------------------------------------------------------------------------
__global__ __launch_bounds__(512, 4) void tree_front(
    const float* __restrict__ x0,
    const u16* __restrict__ wt1, const u16* __restrict__ wt0,
    const float* __restrict__ b1p, const float* __restrict__ b0p,
    u16* __restrict__ h4)
{
    __shared__ __align__(16) u16 buf0[256 * 64];   // 32 KB
    __shared__ __align__(16) u16 buf1[128 * 64];   // 16 KB

    const int l  = threadIdx.x & 63;
    const int w  = threadIdx.x >> 6;   // 0..7
    const int c2 = w & 1;              // col half (32 cols)
    const int wr = w >> 1;             // row split 0..3
    const int lq = l >> 4;
    const int lm = l & 15;
    const int p  = blockIdx.x;
    const float* xbase = x0 + (size_t)p * 511 * 35;

    auto BAR = []() {
        asm volatile("s_waitcnt lgkmcnt(0)" ::: "memory");
        __builtin_amdgcn_s_barrier();
        asm volatile("" ::: "memory");
    };
    auto xload = [&](int lo, int R0) -> XL {
        const float* xr = xbase + (size_t)(lo + R0 + lm) * 35;
        XL v;
        v.A = *(const float4*)(xr + lq * 8);
        v.B = *(const float4*)(xr + lq * 8 + 4);
        if (lq == 0) v.T = *(const float4*)(xr + 31);   // k31..34
        else         v.T = float4{0.f, 0.f, 0.f, 0.f};
        return v;
    };
    auto store16 = [&](u16* bufW, int R0, const f4v& acc0, const f4v& acc1) {
        #pragma unroll
        for (int r = 0; r < 4; r++) {
            int ro = R0 + lq * 4 + r;
            int sw = SWZ(ro);
            bufW[ro*64 + ((c2*32      + lm) ^ sw)] = f2bf(fmaxf(acc0[r], 0.f));
            bufW[ro*64 + ((c2*32 + 16 + lm) ^ sw)] = f2bf(fmaxf(acc1[r], 0.f));
        }
    };

    // ---- leaf: 4 tiles/wave, loads staged 2 ahead; l7/l6 x0 prefetched ----
    XL xl0 = xload(255, wr * 16);
    XL xl1 = xload(255, (wr + 4) * 16);

    s8v wL[2][2]; f4v bi0[2];
    #pragma unroll
    for (int cc = 0; cc < 2; cc++) {
        int col = c2*32 + cc*16 + lm;
        wL[cc][0] = *(const s8v*)(wt0 + col*64 +      lq*8);
        wL[cc][1] = *(const s8v*)(wt0 + col*64 + 32 + lq*8);
        float bv = b0p[col];
        bi0[cc] = (f4v){bv, bv, bv, bv};
    }

    XL x7a = xload(127, wr * 16);      // l7 prefetch (used after BAR1)

    auto leaftile = [&](const XL& xv, int R0) {
        s8v a0 = mk0(xv), a1 = mk1(xv);
        f4v acc0 = bi0[0], acc1 = bi0[1];
        acc0 = mfma16(a0, wL[0][0], acc0);
        acc1 = mfma16(a0, wL[1][0], acc1);
        acc0 = mfma16(a1, wL[0][1], acc0);
        acc1 = mfma16(a1, wL[1][1], acc1);
        store16(buf0, R0, acc0, acc1);
    };

    leaftile(xl0, wr * 16);
    XL xl2 = xload(255, (wr + 8) * 16);
    leaftile(xl1, (wr + 4) * 16);
    XL xl3 = xload(255, (wr + 12) * 16);
    XL x7b = xload(127, (wr + 4) * 16);   // l7 prefetch (2nd tile)
    leaftile(xl2, (wr + 8) * 16);
    XL x6 = xload(63, wr * 16);           // l6 prefetch (used after BAR2)
    leaftile(xl3, (wr + 12) * 16);

    // internal weights (L2-hot)
    s8v wX[2][2], wH[2][4]; f4v bi1[2];
    #pragma unroll
    for (int cc = 0; cc < 2; cc++) {
        int col = c2*32 + cc*16 + lm;
        #pragma unroll
        for (int ks = 0; ks < 2; ks++) wX[cc][ks] = *(const s8v*)(wt1 + col*192 + ks*32 + lq*8);
        #pragma unroll
        for (int ks = 0; ks < 4; ks++) wH[cc][ks] = *(const s8v*)(wt1 + col*192 + 64 + ks*32 + lq*8);
        float bv = b1p[col];
        bi1[cc] = (f4v){bv, bv, bv, bv};
    }

    auto ctile = [&](const u16* bufR, u16* bufW, const XL& xv, int R0) {
        s8v a0 = mk0(xv), a1 = mk1(xv);
        f4v acc0 = bi1[0], acc1 = bi1[1];
        acc0 = mfma16(a0, wX[0][0], acc0);
        acc1 = mfma16(a0, wX[1][0], acc1);
        acc0 = mfma16(a1, wX[0][1], acc0);
        acc1 = mfma16(a1, wX[1][1], acc1);
        int g = R0 + lm;
        #pragma unroll
        for (int ks = 0; ks < 4; ks++) {
            int k0 = ks*32 + lq*8;
            int rr = 2*g + (k0 >> 6);
            s8v a = *(const s8v*)(bufR + rr*64 + ((k0 & 63) ^ SWZ(rr)));
            acc0 = mfma16(a, wH[0][ks], acc0);
            acc1 = mfma16(a, wH[1][ks], acc1);
        }
        store16(bufW, R0, acc0, acc1);
    };

    BAR();
    // ---- l7 (128 rows): buf0 -> buf1, 2 tiles/wave ----
    ctile(buf0, buf1, x7a, wr * 16);
    XL x5; if (wr < 2) x5 = xload(31, wr * 16);    // l5 prefetch
    ctile(buf0, buf1, x7b, (wr + 4) * 16);
    XL x4; if (wr == 0) x4 = xload(15, 0);         // l4 prefetch
    BAR();
    // ---- l6 (64 rows): buf1 -> buf0 ----
    ctile(buf1, buf0, x6, wr * 16);
    BAR();
    // ---- l5 (32 rows): buf0 -> buf1, waves wr<2 ----
    if (wr < 2) ctile(buf0, buf1, x5, wr * 16);
    BAR();
    // ---- l4 (16 rows): buf1 -> global h4, waves wr==0 ----
    if (wr == 0) {
        s8v a0 = mk0(x4), a1 = mk1(x4);
        f4v acc0 = bi1[0], acc1 = bi1[1];
        acc0 = mfma16(a0, wX[0][0], acc0);
        acc1 = mfma16(a0, wX[1][0], acc1);
        acc0 = mfma16(a1, wX[0][1], acc0);
        acc1 = mfma16(a1, wX[1][1], acc1);
        #pragma unroll
        for (int ks = 0; ks < 4; ks++) {
            int k0 = ks*32 + lq*8;
            int rr = 2*lm + (k0 >> 6);
            s8v a = *(const s8v*)(buf1 + rr*64 + ((k0 & 63) ^ SWZ(rr)));
            acc0 = mfma16(a, wH[0][ks], acc0);
            acc1 = mfma16(a, wH[1][ks], acc1);
        }
        #pragma unroll
        for (int r = 0; r < 4; r++) {
            h4[((size_t)p*16 + lq*4 + r) * 64 + c2*32      + lm] = f2bf(fmaxf(acc0[r], 0.f));
            h4[((size_t)p*16 + lq*4 + r) * 64 + c2*32 + 16 + lm] = f2bf(fmaxf(acc1[r], 0.f));
        }
    }
}

// ---------------------------------------------------------------------------
// k3: block = tree p, ONE wave. l3..l0, children via LDS ping-pong, no
// barriers (intra-wave lgkmcnt ordering). All global loads hoisted to entry.
__global__ __launch_bounds__(64) void k3_tail(
    const float* __restrict__ x0,
    const u16* __restrict__ wt1, const float* __restrict__ b1p,
    const u16* __restrict__ h4, float* __restrict__ h0)
{
    __shared__ __align__(16) u16 tb0[32 * 64];
    __shared__ __align__(16) u16 tb1[32 * 64];
    const int l  = threadIdx.x;
    const int lq = l >> 4, lm = l & 15;
    const int p  = blockIdx.x;
    const float* xb = x0 + (size_t)p * 511 * 35;

    auto xload = [&](int lo) -> XL {
        const float* xr = xb + (size_t)(lo + lm) * 35;
        XL v;
        v.A = *(const float4*)(xr + lq * 8);
        v.B = *(const float4*)(xr + lq * 8 + 4);
        if (lq == 0) v.T = *(const float4*)(xr + 31);
        else         v.T = float4{0.f, 0.f, 0.f, 0.f};
        return v;
    };

    // hoisted global loads: x0 rows for all 4 levels + l3 children from h4
    XL X3 = xload(7), X2 = xload(3), X1 = xload(1), X0v = xload(0);
    s8v ch[4];
    #pragma unroll
    for (int ks = 0; ks < 4; ks++) {
        int k0 = ks*32 + lq*8;
        int rr = 2*lm + (k0 >> 6);   // may overread into h0 region (allocated)
        ch[ks] = *(const s8v*)(h4 + ((size_t)p*16 + rr)*64 + (k0 & 63));
    }

    s8v wB[6][4]; f4v bi[4];
    #pragma unroll
    for (int ct = 0; ct < 4; ct++) {
        int col = ct*16 + lm;
        #pragma unroll
        for (int ks = 0; ks < 6; ks++) wB[ks][ct] = *(const s8v*)(wt1 + col*192 + ks*32 + lq*8);
        float bv = b1p[col];
        bi[ct] = (f4v){bv, bv, bv, bv};
    }

    f4v acc[4];
    auto store_lds = [&](u16* buf) {
        #pragma unroll
        for (int r = 0; r < 4; r++) {
            int ro = lq*4 + r; int sw = SWZ(ro);
            #pragma unroll
            for (int ct = 0; ct < 4; ct++)
                buf[ro*64 + ((ct*16 + lm) ^ sw)] = f2bf(fmaxf(acc[ct][r], 0.f));
        }
        asm volatile("s_waitcnt lgkmcnt(0)" ::: "memory");
    };

    // ---- l3 (children in regs) ----
    {
        s8v a0 = mk0(X3), a1 = mk1(X3);
        #pragma unroll
        for (int ct = 0; ct < 4; ct++) {
            acc[ct] = bi[ct];
            acc[ct] = mfma16(a0, wB[0][ct], acc[ct]);
            acc[ct] = mfma16(a1, wB[1][ct], acc[ct]);
        }
        #pragma unroll
        for (int ks = 0; ks < 4; ks++)
            #pragma unroll
            for (int ct = 0; ct < 4; ct++) acc[ct] = mfma16(ch[ks], wB[2 + ks][ct], acc[ct]);
        store_lds(tb0);
    }

    auto level = [&](const XL& xv, const u16* bufR) {
        s8v a0 = mk0(xv), a1 = mk1(xv);
        #pragma unroll
        for (int ct = 0; ct < 4; ct++) {
            acc[ct] = bi[ct];
            acc[ct] = mfma16(a0, wB[0][ct], acc[ct]);
            acc[ct] = mfma16(a1, wB[1][ct], acc[ct]);
        }
        #pragma unroll
        for (int ks = 0; ks < 4; ks++) {
            int k0 = ks*32 + lq*8;
            int rr = 2*lm + (k0 >> 6);
            s8v a = *(const s8v*)(bufR + rr*64 + ((k0 & 63) ^ SWZ(rr)));
            #pragma unroll
            for (int ct = 0; ct < 4; ct++) acc[ct] = mfma16(a, wB[2 + ks][ct], acc[ct]);
        }
    };
    level(X2, tb0); store_lds(tb1);
    level(X1, tb1); store_lds(tb0);
    level(X0v, tb0);
    if (lq == 0) {
        #pragma unroll
        for (int ct = 0; ct < 4; ct++)
            h0[(size_t)p*64 + ct*16 + lm] = fmaxf(acc[ct][0], 0.f);
    }
}

// ---------------------------------------------------------------------------
__global__ void mean_kernel(const float* __restrict__ h0, float* __restrict__ mh)
{
    int idx = blockIdx.x * blockDim.x + threadIdx.x;   // 512*64
    if (idx < 512 * 64) {
        int g = idx >> 6, h = idx & 63;
        float s = 0.f;
        #pragma unroll
        for (int q = 0; q < 5; q++) s += h0[(size_t)(g * 5 + q) * 64 + h];
        mh[idx] = s * 0.2f;
    }
}

__global__ __launch_bounds__(64) void head_kernel(const float* __restrict__ x,
                                                  const float* __restrict__ mh,
                                                  const float* __restrict__ Wfc1,
                                                  const float* __restrict__ bfc1,
                                                  const float* __restrict__ Wfc2,
                                                  const float* __restrict__ bfc2,
                                                  float* __restrict__ out)
{
    __shared__ float sw[64];
    __shared__ float sh[64];
    int b = blockIdx.x, h = threadIdx.x;

    float a0 = 0.f, a1 = 0.f, a2 = 0.f, a3 = 0.f;
    const float* xr = x + (size_t)b * 512;
    for (int g = 0; g < 512; g += 4) {
        a0 = fmaf(xr[g + 0], mh[(g + 0) * 64 + h], a0);
        a1 = fmaf(xr[g + 1], mh[(g + 1) * 64 + h], a1);
        a2 = fmaf(xr[g + 2], mh[(g + 2) * 64 + h], a2);
        a3 = fmaf(xr[g + 3], mh[(g + 3) * 64 + h], a3);
    }
    sw[h] = (a0 + a1) + (a2 + a3);
    __syncthreads();

    float acc = bfc1[h];
    #pragma unroll 8
    for (int k = 0; k < 64; k++) acc = fmaf(Wfc1[h * 64 + k], sw[k], acc);
    sh[h] = fmaxf(acc, 0.f);
    __syncthreads();

    if (h < 8) {
        float o = bfc2[h];
        #pragma unroll 8
        for (int f = 0; f < 64; f++) o = fmaf(Wfc2[h * 64 + f], sh[f], o);
        out[(size_t)b * 8 + h] = o;
    }
}

// ---------------------------------------------------------------------------
extern "C" void kernel_launch(void* const* d_in, const int* in_sizes, int n_in,
                              void* d_out, int out_size, void* d_ws, size_t ws_size,
                              hipStream_t stream)
{
    (void)in_sizes; (void)n_in; (void)out_size; (void)ws_size;
    const float* x     = (const float*)d_in[0];
    const float* x0    = (const float*)d_in[1];
    const float* W_emb = (const float*)d_in[2];
    const float* b_emb = (const float*)d_in[3];
    const float* W0    = (const float*)d_in[4];
    const float* b0    = (const float*)d_in[5];
    const float* W1    = (const float*)d_in[6];
    const float* b1    = (const float*)d_in[7];
    const float* Wfc1  = (const float*)d_in[8];
    const float* bfc1  = (const float*)d_in[9];
    const float* Wfc2  = (const float*)d_in[10];
    const float* bfc2  = (const float*)d_in[11];
    float* out = (float*)d_out;

    u16* wt1   = (u16*)d_ws;                 // 64*192
    u16* wt0   = wt1 + 64 * 192;             // 64*64
    float* b1p = (float*)(wt0 + 64 * 64);
    float* b0p = b1p + 64;
    u16* h4    = (u16*)(b0p + 64);           // 2560*16*64 bf16 = 5.24 MB
    float* h0  = (float*)(h4 + (size_t)2560 * 16 * 64);   // 2560*64 f32
    float* mh  = h0 + 2560 * 64;             // 512*64 f32
    // total ws need ~6.1 MB (R4 validated ws_size >= 27 MB)

    prep_kernel<<<65, 256, 0, stream>>>(W_emb, b_emb, W0, b0, W1, b1, wt1, wt0, b1p, b0p);
    tree_front<<<2560, 512, 0, stream>>>(x0, wt1, wt0, b1p, b0p, h4);
    k3_tail<<<2560, 64, 0, stream>>>(x0, wt1, b1p, h4, h0);
    mean_kernel<<<128, 256, 0, stream>>>(h0, mh);
    head_kernel<<<512, 64, 0, stream>>>(x, mh, Wfc1, bfc1, Wfc2, bfc2, out);
}

// Round 7
// 104.158 us; speedup vs baseline: 1.8921x; 1.1351x over previous
//
#include <hip/hip_runtime.h>
#include <hip/hip_bf16.h>

// ---------------------------------------------------------------------------
// Tree-MLP, round 7 (= round 6 with pragma-placement compile fix).
// Root cause found in R5: x0 rows are 140B, unaligned, lane-strided -> every
// A-frag load was a swarm of split/scattered transactions (latency-bound,
// all counters low). Fix: per-block coalesced dword staging of the whole
// tree's x0 into padded bf16 LDS images [row][40]; A-frags become single
// aligned ds_read_b128. Compute structure identical to validated R5.
// ---------------------------------------------------------------------------

typedef __attribute__((ext_vector_type(8))) short s8v;   // 8 bf16
typedef __attribute__((ext_vector_type(4))) float f4v;   // MFMA C/D
typedef unsigned short u16;

__device__ __forceinline__ u16 f2bf(float f) {
    return __builtin_bit_cast(u16, __float2bfloat16(f));
}
__device__ __forceinline__ f4v mfma16(s8v a, s8v b, f4v c) {
    return __builtin_amdgcn_mfma_f32_16x16x32_bf16(a, b, c, 0, 0, 0);
}
// LDS swizzle for h-buffers: 8-granular XOR of h-index with row bits {0,2,3}
#define SWZ(r) ((((r) & 1) | (((r) >> 1) & 6)) << 3)

// tail A-frag from padded LDS row (cols 32..39, 35..39 are zero); lanes with
// lq!=0 must supply zeros (their k >= 40 slots are padding of the K=64 step)
__device__ __forceinline__ s8v xtail_lds(const u16* xr, int lq) {
    s8v v = *(const s8v*)(xr + 32);
    if (lq != 0) v = (s8v){0,0,0,0,0,0,0,0};
    return v;
}

// ---------------------------------------------------------------------------
__global__ void prep_kernel(const float* __restrict__ W_emb, const float* __restrict__ b_emb,
                            const float* __restrict__ W0, const float* __restrict__ b0,
                            const float* __restrict__ W1, const float* __restrict__ b1,
                            u16* __restrict__ wt1, u16* __restrict__ wt0,
                            float* __restrict__ b1p, float* __restrict__ b0p)
{
    int idx = blockIdx.x * 256 + threadIdx.x;
    if (idx < 64 * 192) {
        int h = idx / 192, k = idx % 192;
        float v;
        if (k < 32) { v = 0.f; for (int e = 0; e < 64; e++) v = fmaf(W1[h*195+e], W_emb[e*32+k], v); }
        else if (k < 35)  v = W1[h*195 + 64 + (k - 32)];
        else if (k < 64)  v = 0.f;
        else              v = W1[h*195 + 67 + (k - 64)];   // hL(64) then hR(64)
        wt1[h*192 + k] = f2bf(v);
    } else if (idx < 64*192 + 64*64) {
        int j = idx - 64*192; int h = j >> 6, k = j & 63;
        float v;
        if (k < 32)      { v = 0.f; for (int e = 0; e < 64; e++) v = fmaf(W0[h*67+e], W_emb[e*32+k], v); }
        else if (k < 35)   v = W0[h*67 + 64 + (k - 32)];
        else               v = 0.f;
        wt0[h*64 + k] = f2bf(v);
    } else if (idx < 64*192 + 64*64 + 64) {
        int h = idx - (64*192 + 64*64);
        float v = b1[h];
        for (int e = 0; e < 64; e++) v = fmaf(W1[h*195+e], b_emb[e], v);
        b1p[h] = v;
    } else if (idx < 64*192 + 64*64 + 128) {
        int h = idx - (64*192 + 64*64 + 64);
        float v = b0[h];
        for (int e = 0; e < 64; e++) v = fmaf(W0[h*67+e], b_emb[e], v);
        b0p[h] = v;
    }
}

// ---------------------------------------------------------------------------
__global__ __launch_bounds__(512, 4) void tree_front(
    const float* __restrict__ x0,
    const u16* __restrict__ wt1, const u16* __restrict__ wt0,
    const float* __restrict__ b1p, const float* __restrict__ b0p,
    u16* __restrict__ h4)
{
    // padded x0 images: [row][40] bf16 (80B rows -> aligned b128 frags)
    __shared__ __align__(16) u16 xleaf[257 * 40];  // nodes 255..510; later reused for nodes 0..126
    __shared__ __align__(16) u16 xmid [129 * 40];  // nodes 127..254
    __shared__ __align__(16) u16 buf0[256 * 64];   // 32 KB
    __shared__ __align__(16) u16 buf1[128 * 64];   // 16 KB
    // total ~78.2 KB -> 2 blocks/CU

    const int tid = threadIdx.x;
    const int l  = tid & 63;
    const int w  = tid >> 6;   // 0..7
    const int c2 = w & 1;      // col half (32 cols)
    const int wr = w >> 1;     // row split 0..3
    const int lq = l >> 4;
    const int lm = l & 15;
    const int p  = blockIdx.x;
    const float* xg = x0 + (size_t)p * 511 * 35;

    auto BAR = []() {
        asm volatile("s_waitcnt lgkmcnt(0)" ::: "memory");
        __builtin_amdgcn_s_barrier();
        asm volatile("" ::: "memory");
    };

    // ---- S0: issue ALL x0 staging loads as coalesced dword streams ----
    float sA[18], sB[9], sC[9];
    const float* gA = xg + 255 * 35;   // leaf: 256 rows = 8960 dwords
    #pragma unroll
    for (int t = 0; t < 18; t++) { int i = t*512 + tid; sA[t] = (i < 8960) ? gA[i] : 0.f; }
    const float* gB = xg + 127 * 35;   // l7: 128 rows = 4480 dwords
    #pragma unroll
    for (int t = 0; t < 9; t++)  { int i = t*512 + tid; sB[t] = (i < 4480) ? gB[i] : 0.f; }
    const float* gC = xg;              // nodes 0..126: 4445 dwords
    #pragma unroll
    for (int t = 0; t < 9; t++)  { int i = t*512 + tid; sC[t] = (i < 4445) ? gC[i] : 0.f; }

    // zero pad columns 35..39 (tail-frag zeros; never overwritten afterwards)
    if (tid < 256) {
        int b = tid * 40;
        for (int c = 35; c < 40; c++) xleaf[b + c] = 0;
        if (tid == 255) {
            for (int c = 0; c < 40; c++) xleaf[256 * 40 + c] = 0;   // guard row
        }
    } else if (tid < 384) {
        int b = (tid - 256) * 40;
        for (int c = 35; c < 40; c++) xmid[b + c] = 0;
        if (tid == 383) {
            for (int c = 0; c < 40; c++) xmid[128 * 40 + c] = 0;    // guard row
        }
    }

    // leaf weights
    s8v wL[2][2]; f4v bi0[2];
    #pragma unroll
    for (int cc = 0; cc < 2; cc++) {
        int col = c2*32 + cc*16 + lm;
        wL[cc][0] = *(const s8v*)(wt0 + col*64 +      lq*8);
        wL[cc][1] = *(const s8v*)(wt0 + col*64 + 32 + lq*8);
        float bv = b0p[col];
        bi0[cc] = (f4v){bv, bv, bv, bv};
    }

    // write leaf region (waits only on sA loads)
    #pragma unroll
    for (int t = 0; t < 18; t++) {
        int i = t*512 + tid;
        if (i < 8960) { int row = i / 35, col = i - row*35; xleaf[row*40 + col] = f2bf(sA[t]); }
    }
    BAR();   // xleaf ready

    auto store16 = [&](u16* bufW, int R0, const f4v& acc0, const f4v& acc1) {
        #pragma unroll
        for (int r = 0; r < 4; r++) {
            int ro = R0 + lq * 4 + r;
            int sw = SWZ(ro);
            bufW[ro*64 + ((c2*32      + lm) ^ sw)] = f2bf(fmaxf(acc0[r], 0.f));
            bufW[ro*64 + ((c2*32 + 16 + lm) ^ sw)] = f2bf(fmaxf(acc1[r], 0.f));
        }
    };

    // ---- leaf: 4 tiles/wave from LDS frags ----
    #pragma unroll
    for (int t = 0; t < 4; t++) {
        int R0 = (wr + 4*t) * 16;
        const u16* xr = xleaf + (R0 + lm) * 40;
        s8v a0 = *(const s8v*)(xr + lq*8);
        s8v a1 = xtail_lds(xr, lq);
        f4v acc0 = bi0[0], acc1 = bi0[1];
        acc0 = mfma16(a0, wL[0][0], acc0);
        acc1 = mfma16(a0, wL[1][0], acc1);
        acc0 = mfma16(a1, wL[0][1], acc0);
        acc1 = mfma16(a1, wL[1][1], acc1);
        store16(buf0, R0, acc0, acc1);
    }

    // internal weights (L2-hot)
    s8v wX[2][2], wH[2][4]; f4v bi1[2];
    #pragma unroll
    for (int cc = 0; cc < 2; cc++) {
        int col = c2*32 + cc*16 + lm;
        #pragma unroll
        for (int ks = 0; ks < 2; ks++) wX[cc][ks] = *(const s8v*)(wt1 + col*192 + ks*32 + lq*8);
        #pragma unroll
        for (int ks = 0; ks < 4; ks++) wH[cc][ks] = *(const s8v*)(wt1 + col*192 + 64 + ks*32 + lq*8);
        float bv = b1p[col];
        bi1[cc] = (f4v){bv, bv, bv, bv};
    }

    // write l7 x-region during leaf->l7 window
    #pragma unroll
    for (int t = 0; t < 9; t++) {
        int i = t*512 + tid;
        if (i < 4480) { int row = i / 35, col = i - row*35; xmid[row*40 + col] = f2bf(sB[t]); }
    }
    BAR();   // buf0 + xmid ready

    auto ctile = [&](const u16* bufR, u16* bufW, const u16* xb, int xr0, int R0) {
        const u16* xr = xb + (xr0 + lm) * 40;
        s8v a0 = *(const s8v*)(xr + lq*8);
        s8v a1 = xtail_lds(xr, lq);
        f4v acc0 = bi1[0], acc1 = bi1[1];
        acc0 = mfma16(a0, wX[0][0], acc0);
        acc1 = mfma16(a0, wX[1][0], acc1);
        acc0 = mfma16(a1, wX[0][1], acc0);
        acc1 = mfma16(a1, wX[1][1], acc1);
        int g = R0 + lm;
        #pragma unroll
        for (int ks = 0; ks < 4; ks++) {
            int k0 = ks*32 + lq*8;
            int rr = 2*g + (k0 >> 6);
            s8v a = *(const s8v*)(bufR + rr*64 + ((k0 & 63) ^ SWZ(rr)));
            acc0 = mfma16(a, wH[0][ks], acc0);
            acc1 = mfma16(a, wH[1][ks], acc1);
        }
        store16(bufW, R0, acc0, acc1);
    };

    // ---- l7 (128 rows): buf0 -> buf1, x from xmid ----
    ctile(buf0, buf1, xmid, wr * 16,        wr * 16);
    ctile(buf0, buf1, xmid, (wr + 4) * 16,  (wr + 4) * 16);

    // write remaining x-region (nodes 0..126) into xleaf (free after leaf)
    #pragma unroll
    for (int t = 0; t < 9; t++) {
        int i = t*512 + tid;
        if (i < 4445) { int row = i / 35, col = i - row*35; xleaf[row*40 + col] = f2bf(sC[t]); }
    }
    BAR();   // buf1 + xrest ready

    // ---- l6 (64 rows): buf1 -> buf0, x rows 63..126 ----
    ctile(buf1, buf0, xleaf, 63 + wr * 16, wr * 16);
    BAR();
    // ---- l5 (32 rows): buf0 -> buf1, waves wr<2, x rows 31..62 ----
    if (wr < 2) ctile(buf0, buf1, xleaf, 31 + wr * 16, wr * 16);
    BAR();
    // ---- l4 (16 rows): buf1 -> global h4, waves wr==0, x rows 15..30 ----
    if (wr == 0) {
        const u16* xr = xleaf + (15 + lm) * 40;
        s8v a0 = *(const s8v*)(xr + lq*8);
        s8v a1 = xtail_lds(xr, lq);
        f4v acc0 = bi1[0], acc1 = bi1[1];
        acc0 = mfma16(a0, wX[0][0], acc0);
        acc1 = mfma16(a0, wX[1][0], acc1);
        acc0 = mfma16(a1, wX[0][1], acc0);
        acc1 = mfma16(a1, wX[1][1], acc1);
        #pragma unroll
        for (int ks = 0; ks < 4; ks++) {
            int k0 = ks*32 + lq*8;
            int rr = 2*lm + (k0 >> 6);
            s8v a = *(const s8v*)(buf1 + rr*64 + ((k0 & 63) ^ SWZ(rr)));
            acc0 = mfma16(a, wH[0][ks], acc0);
            acc1 = mfma16(a, wH[1][ks], acc1);
        }
        #pragma unroll
        for (int r = 0; r < 4; r++) {
            h4[((size_t)p*16 + lq*4 + r) * 64 + c2*32      + lm] = f2bf(fmaxf(acc0[r], 0.f));
            h4[((size_t)p*16 + lq*4 + r) * 64 + c2*32 + 16 + lm] = f2bf(fmaxf(acc1[r], 0.f));
        }
    }
}

// ---------------------------------------------------------------------------
// k3: block = tree p, ONE wave. l3..l0, children via LDS ping-pong, no
// barriers (intra-wave lgkmcnt ordering). All global loads hoisted to entry.
struct XL { float4 A, B, T; };
__device__ __forceinline__ s8v mk0(const XL& v) {
    s8v r;
    r[0]=(short)f2bf(v.A.x); r[1]=(short)f2bf(v.A.y); r[2]=(short)f2bf(v.A.z); r[3]=(short)f2bf(v.A.w);
    r[4]=(short)f2bf(v.B.x); r[5]=(short)f2bf(v.B.y); r[6]=(short)f2bf(v.B.z); r[7]=(short)f2bf(v.B.w);
    return r;
}
__device__ __forceinline__ s8v mk1(const XL& v) {
    s8v r = {0,0,0,0,0,0,0,0};
    r[0]=(short)f2bf(v.T.y); r[1]=(short)f2bf(v.T.z); r[2]=(short)f2bf(v.T.w);
    return r;
}

__global__ __launch_bounds__(64) void k3_tail(
    const float* __restrict__ x0,
    const u16* __restrict__ wt1, const float* __restrict__ b1p,
    const u16* __restrict__ h4, float* __restrict__ h0)
{
    __shared__ __align__(16) u16 tb0[32 * 64];
    __shared__ __align__(16) u16 tb1[32 * 64];
    const int l  = threadIdx.x;
    const int lq = l >> 4, lm = l & 15;
    const int p  = blockIdx.x;
    const float* xb = x0 + (size_t)p * 511 * 35;

    auto xload = [&](int lo) -> XL {
        const float* xr = xb + (size_t)(lo + lm) * 35;
        XL v;
        v.A = *(const float4*)(xr + lq * 8);
        v.B = *(const float4*)(xr + lq * 8 + 4);
        if (lq == 0) v.T = *(const float4*)(xr + 31);
        else         v.T = float4{0.f, 0.f, 0.f, 0.f};
        return v;
    };

    XL X3 = xload(7), X2 = xload(3), X1 = xload(1), X0v = xload(0);
    s8v ch[4];
    #pragma unroll
    for (int ks = 0; ks < 4; ks++) {
        int k0 = ks*32 + lq*8;
        int rr = 2*lm + (k0 >> 6);   // may overread into h0 region (allocated)
        ch[ks] = *(const s8v*)(h4 + ((size_t)p*16 + rr)*64 + (k0 & 63));
    }

    s8v wB[6][4]; f4v bi[4];
    #pragma unroll
    for (int ct = 0; ct < 4; ct++) {
        int col = ct*16 + lm;
        #pragma unroll
        for (int ks = 0; ks < 6; ks++) wB[ks][ct] = *(const s8v*)(wt1 + col*192 + ks*32 + lq*8);
        float bv = b1p[col];
        bi[ct] = (f4v){bv, bv, bv, bv};
    }

    f4v acc[4];
    auto store_lds = [&](u16* buf) {
        #pragma unroll
        for (int r = 0; r < 4; r++) {
            int ro = lq*4 + r; int sw = SWZ(ro);
            #pragma unroll
            for (int ct = 0; ct < 4; ct++)
                buf[ro*64 + ((ct*16 + lm) ^ sw)] = f2bf(fmaxf(acc[ct][r], 0.f));
        }
        asm volatile("s_waitcnt lgkmcnt(0)" ::: "memory");
    };

    {
        s8v a0 = mk0(X3), a1 = mk1(X3);
        #pragma unroll
        for (int ct = 0; ct < 4; ct++) {
            acc[ct] = bi[ct];
            acc[ct] = mfma16(a0, wB[0][ct], acc[ct]);
            acc[ct] = mfma16(a1, wB[1][ct], acc[ct]);
        }
        #pragma unroll
        for (int ks = 0; ks < 4; ks++)
            #pragma unroll
            for (int ct = 0; ct < 4; ct++) acc[ct] = mfma16(ch[ks], wB[2 + ks][ct], acc[ct]);
        store_lds(tb0);
    }

    auto level = [&](const XL& xv, const u16* bufR) {
        s8v a0 = mk0(xv), a1 = mk1(xv);
        #pragma unroll
        for (int ct = 0; ct < 4; ct++) {
            acc[ct] = bi[ct];
            acc[ct] = mfma16(a0, wB[0][ct], acc[ct]);
            acc[ct] = mfma16(a1, wB[1][ct], acc[ct]);
        }
        #pragma unroll
        for (int ks = 0; ks < 4; ks++) {
            int k0 = ks*32 + lq*8;
            int rr = 2*lm + (k0 >> 6);
            s8v a = *(const s8v*)(bufR + rr*64 + ((k0 & 63) ^ SWZ(rr)));
            #pragma unroll
            for (int ct = 0; ct < 4; ct++) acc[ct] = mfma16(a, wB[2 + ks][ct], acc[ct]);
        }
    };
    level(X2, tb0); store_lds(tb1);
    level(X1, tb1); store_lds(tb0);
    level(X0v, tb0);
    if (lq == 0) {
        #pragma unroll
        for (int ct = 0; ct < 4; ct++)
            h0[(size_t)p*64 + ct*16 + lm] = fmaxf(acc[ct][0], 0.f);
    }
}

// ---------------------------------------------------------------------------
__global__ void mean_kernel(const float* __restrict__ h0, float* __restrict__ mh)
{
    int idx = blockIdx.x * blockDim.x + threadIdx.x;   // 512*64
    if (idx < 512 * 64) {
        int g = idx >> 6, h = idx & 63;
        float s = 0.f;
        #pragma unroll
        for (int q = 0; q < 5; q++) s += h0[(size_t)(g * 5 + q) * 64 + h];
        mh[idx] = s * 0.2f;
    }
}

__global__ __launch_bounds__(64) void head_kernel(const float* __restrict__ x,
                                                  const float* __restrict__ mh,
                                                  const float* __restrict__ Wfc1,
                                                  const float* __restrict__ bfc1,
                                                  const float* __restrict__ Wfc2,
                                                  const float* __restrict__ bfc2,
                                                  float* __restrict__ out)
{
    __shared__ float sw[64];
    __shared__ float sh[64];
    int b = blockIdx.x, h = threadIdx.x;

    float a0 = 0.f, a1 = 0.f, a2 = 0.f, a3 = 0.f;
    const float* xr = x + (size_t)b * 512;
    for (int g = 0; g < 512; g += 4) {
        a0 = fmaf(xr[g + 0], mh[(g + 0) * 64 + h], a0);
        a1 = fmaf(xr[g + 1], mh[(g + 1) * 64 + h], a1);
        a2 = fmaf(xr[g + 2], mh[(g + 2) * 64 + h], a2);
        a3 = fmaf(xr[g + 3], mh[(g + 3) * 64 + h], a3);
    }
    sw[h] = (a0 + a1) + (a2 + a3);
    __syncthreads();

    float acc = bfc1[h];
    #pragma unroll 8
    for (int k = 0; k < 64; k++) acc = fmaf(Wfc1[h * 64 + k], sw[k], acc);
    sh[h] = fmaxf(acc, 0.f);
    __syncthreads();

    if (h < 8) {
        float o = bfc2[h];
        #pragma unroll 8
        for (int f = 0; f < 64; f++) o = fmaf(Wfc2[h * 64 + f], sh[f], o);
        out[(size_t)b * 8 + h] = o;
    }
}

// ---------------------------------------------------------------------------
extern "C" void kernel_launch(void* const* d_in, const int* in_sizes, int n_in,
                              void* d_out, int out_size, void* d_ws, size_t ws_size,
                              hipStream_t stream)
{
    (void)in_sizes; (void)n_in; (void)out_size; (void)ws_size;
    const float* x     = (const float*)d_in[0];
    const float* x0    = (const float*)d_in[1];
    const float* W_emb = (const float*)d_in[2];
    const float* b_emb = (const float*)d_in[3];
    const float* W0    = (const float*)d_in[4];
    const float* b0    = (const float*)d_in[5];
    const float* W1    = (const float*)d_in[6];
    const float* b1    = (const float*)d_in[7];
    const float* Wfc1  = (const float*)d_in[8];
    const float* bfc1  = (const float*)d_in[9];
    const float* Wfc2  = (const float*)d_in[10];
    const float* bfc2  = (const float*)d_in[11];
    float* out = (float*)d_out;

    u16* wt1   = (u16*)d_ws;                 // 64*192
    u16* wt0   = wt1 + 64 * 192;             // 64*64
    float* b1p = (float*)(wt0 + 64 * 64);
    float* b0p = b1p + 64;
    u16* h4    = (u16*)(b0p + 64);           // 2560*16*64 bf16
    float* h0  = (float*)(h4 + (size_t)2560 * 16 * 64);   // 2560*64 f32
    float* mh  = h0 + 2560 * 64;             // 512*64 f32

    prep_kernel<<<65, 256, 0, stream>>>(W_emb, b_emb, W0, b0, W1, b1, wt1, wt0, b1p, b0p);
    tree_front<<<2560, 512, 0, stream>>>(x0, wt1, wt0, b1p, b0p, h4);
    k3_tail<<<2560, 64, 0, stream>>>(x0, wt1, b1p, h4, h0);
    mean_kernel<<<128, 256, 0, stream>>>(h0, mh);
    head_kernel<<<512, 64, 0, stream>>>(x, mh, Wfc1, bfc1, Wfc2, bfc2, out);
}